// Round 2
// baseline (102.628 us; speedup 1.0000x reference)
//
#include <hip/hip_runtime.h>

#define NB   2
#define NCO  8
#define NCI  8
#define ND   8
#define NGH  16
#define NGW  16
#define NH   512
#define NW   512
#define NCHUNK 5   // ceil(35*35 / 256)

// One block per (b, cell_y, cell_x, chunk); 1 pixel per thread.
// Grid-cell values are wave-uniform -> scalar loads + SGPR operands in fma.
__global__ __launch_bounds__(256, 4) void bslice_kernel(
    const float* __restrict__ grid,
    const float* __restrict__ guide,
    const float* __restrict__ inp,
    float* __restrict__ out)
{
    const int tid   = threadIdx.x;
    const int cx    = blockIdx.x;          // 0..14
    const int cy    = blockIdx.y;          // 0..14
    const int bz    = blockIdx.z;          // 0..9
    const int b     = bz & 1;
    const int chunk = bz >> 1;             // 0..4

    // pixel range covered by this cell: x with min(floor(x*15/511),14) == cx
    const int xs = (cx * (NW - 1) + (NGW - 2)) / (NGW - 1);            // ceil(cx*511/15)
    const int xe = (cx == NGW - 2) ? NW : (((cx + 1) * (NW - 1) + (NGW - 2)) / (NGW - 1));
    const int ys = (cy * (NH - 1) + (NGH - 2)) / (NGH - 1);
    const int ye = (cy == NGH - 2) ? NH : (((cy + 1) * (NH - 1) + (NGH - 2)) / (NGH - 1));

    const unsigned wcell = (unsigned)(xe - xs);
    const int npix = (int)wcell * (ye - ys);

    const int i = chunk * 256 + tid;
    const bool valid = (i < npix);
    const unsigned ii = valid ? (unsigned)i : 0u;
    const unsigned q  = ii / wcell;
    const int py = ys + (int)q;
    const int px = xs + (int)(ii - q * wcell);

    const float step = (float)(NGH - 1) / (float)(NH - 1);   // 15/511
    const float wy = (float)py * step - (float)cy;           // in (0,1]
    const float wx = (float)px * step - (float)cx;
    float wgt[4];
    wgt[0] = (1.f - wy) * (1.f - wx);
    wgt[1] = (1.f - wy) * wx;
    wgt[2] = wy * (1.f - wx);
    wgt[3] = wy * wx;

    const int off = py * NW + px;
    const size_t inbase = (size_t)b * NCI * NH * NW;

    // Per-pixel z-tent accumulators: S0[z] = sum_ci tent_z(ci)*inp(ci),
    // S1[z] = (1/8) * sum_ci tent_z(ci)  (bias mean folded in).
    float S0[8], S1[8];
    #pragma unroll
    for (int z = 0; z < 8; ++z) { S0[z] = 0.f; S1[z] = 0.f; }

    const float* gp = guide + inbase + off;
    const float* vp = inp   + inbase + off;
    #pragma unroll
    for (int ci = 0; ci < NCI; ++ci) {
        float g = gp[(size_t)ci * NH * NW];
        float v = vp[(size_t)ci * NH * NW];
        float zp = fminf(fmaxf(g * 7.0f, 0.0f), 7.0f);
        #pragma unroll
        for (int z = 0; z < 8; ++z) {
            float a = fmaxf(0.0f, 1.0f - fabsf(zp - (float)z));
            S0[z] = fmaf(a, v, S0[z]);
            S1[z] += a;
        }
    }
    #pragma unroll
    for (int z = 0; z < 8; ++z) S1[z] *= 0.125f;

    const size_t obase = (size_t)b * NCO * NH * NW;

    // grid element (co,k,z,dy,dx) at:
    //   ((((b*8+co)*2+k)*8+z)*16 + (cy+dy))*16 + (cx+dx)
    // All indices below are blockIdx-uniform -> scalar loads.
    #pragma unroll 1
    for (int co = 0; co < NCO; ++co) {
        const float* gbase = grid
            + ((size_t)(b * NCO + co) * 2) * (ND * NGH * NGW)
            + cy * NGW + cx;
        float acc = 0.f;
        #pragma unroll
        for (int dy = 0; dy < 2; ++dy) {
            #pragma unroll
            for (int dx = 0; dx < 2; ++dx) {
                const int cidx = dy * NGW + dx;
                float t = 0.f;
                #pragma unroll
                for (int z = 0; z < 8; ++z)
                    t = fmaf(S0[z], gbase[z * (NGH * NGW) + cidx], t);
                #pragma unroll
                for (int z = 0; z < 8; ++z)
                    t = fmaf(S1[z], gbase[(ND + z) * (NGH * NGW) + cidx], t);
                acc = fmaf(wgt[dy * 2 + dx], t, acc);
            }
        }
        if (valid)
            out[obase + (size_t)co * NH * NW + off] = acc;
    }
}

extern "C" void kernel_launch(void* const* d_in, const int* in_sizes, int n_in,
                              void* d_out, int out_size, void* d_ws, size_t ws_size,
                              hipStream_t stream) {
    const float* grid  = (const float*)d_in[0];
    const float* guide = (const float*)d_in[1];
    const float* inp   = (const float*)d_in[2];
    float* out = (float*)d_out;

    dim3 g(NGW - 1, NGH - 1, NB * NCHUNK);   // (15, 15, 10) = 2250 blocks
    bslice_kernel<<<g, 256, 0, stream>>>(grid, guide, inp, out);
}